// Round 1
// baseline (326.811 us; speedup 1.0000x reference)
//
#include <hip/hip_runtime.h>

#define CIN 512
#define COUT 512
#define HH 64
#define WW 64
#define BB 8
#define KTOT 4608   // 512*9

typedef __attribute__((ext_vector_type(8))) short short8;
typedef __attribute__((ext_vector_type(4))) float f32x4;

__device__ inline unsigned short f2bf(float f) {
    unsigned int u = __float_as_uint(f);
    u += 0x7FFFu + ((u >> 16) & 1u);   // round-to-nearest-even
    return (unsigned short)(u >> 16);
}

// ---------------- Phase 0: x [b][i][y][x] fp32 -> XT [b][y][x][i] bf16 ----------------
__global__ __launch_bounds__(256) void xpose_kernel(const float* __restrict__ x,
                                                    unsigned short* __restrict__ xt) {
    __shared__ float tile[32 * 65];
    const int ic = blockIdx.x;   // 16 groups of 32 channels
    const int y  = blockIdx.y;
    const int b  = blockIdx.z;
    const int t  = threadIdx.x;
#pragma unroll
    for (int it = 0; it < 8; ++it) {
        int e = it * 256 + t;
        int ii = e >> 6, xx = e & 63;
        tile[ii * 65 + xx] = x[(((size_t)(b * CIN + ic * 32 + ii) * HH + y) << 6) + xx];
    }
    __syncthreads();
#pragma unroll
    for (int it = 0; it < 8; ++it) {
        int g = it * 256 + t;
        int xx = g >> 5, ii = g & 31;
        xt[(((size_t)(b * HH + y) * WW + xx) << 9) + ic * 32 + ii] = f2bf(tile[ii * 65 + xx]);
    }
}

// ---------------- Phase 1: modulated packed weights Wp[b][tap][o][i] bf16 ----------------
__global__ __launch_bounds__(256) void modw_kernel(const float* __restrict__ weight,
                                                   const float* __restrict__ style,
                                                   unsigned short* __restrict__ wp) {
    __shared__ float q[KTOT];
    __shared__ float redbuf[4];
    __shared__ float s_scale;
    const int o = blockIdx.x;
    const int b = blockIdx.y;
    const int t = threadIdx.x;
    const float* wrow = weight + (size_t)o * KTOT;   // [i][tap] contiguous: e = i*9+tap
    const float* st   = style + b * CIN;

    float ss = 0.f;
#pragma unroll
    for (int it = 0; it < 18; ++it) {
        int e = it * 256 + t;
        int i = e / 9;
        float v = wrow[e] * (st[i] + 1.0f);
        q[e] = v;
        ss += v * v;
    }
#pragma unroll
    for (int off = 32; off > 0; off >>= 1) ss += __shfl_down(ss, off, 64);
    int wid = t >> 6;
    if ((t & 63) == 0) redbuf[wid] = ss;
    __syncthreads();
    if (t == 0) {
        float S = redbuf[0] + redbuf[1] + redbuf[2] + redbuf[3];
        const float c = 1.0f / sqrtf((float)KTOT);
        s_scale = c * rsqrtf(S * (1.0f / (float)KTOT) + 1e-8f);
    }
    __syncthreads();
    float scale = s_scale;
#pragma unroll
    for (int tap = 0; tap < 9; ++tap) {
        unsigned short* drow = wp + (((size_t)(b * 9 + tap) * COUT + o) << 9);
        for (int i = t; i < CIN; i += 256) {
            drow[i] = f2bf(q[i * 9 + tap] * scale);
        }
    }
}

// ---------------- Phase 2: implicit-GEMM conv ----------------
// block: 128 out-ch x (2 rows x 64 cols), 4 waves each [64 o][64 s]
// LDS X tile: [4 input rows][66 cols][64 ch] bf16, row stride padded to 72 shorts (144B)
#define LSTRIDE 72
#define LCOLS 66
__global__ __launch_bounds__(256) void conv_kernel(const unsigned short* __restrict__ wp,
                                                   const unsigned short* __restrict__ xt,
                                                   const float* __restrict__ bias,
                                                   float* __restrict__ out) {
    __shared__ __align__(16) unsigned short xs[4 * LCOLS * LSTRIDE];
    const int yb = blockIdx.x;   // 32 row-pairs
    const int ob = blockIdx.y;   // 4 o-blocks of 128
    const int b  = blockIdx.z;
    const int tid = threadIdx.x;
    const int lane = tid & 63, wid = tid >> 6;
    const int l15 = lane & 15, l4 = lane >> 4;
    const int o0w = (wid & 1) * 64;   // wave's o-offset within the 128 block
    const int row_w = wid >> 1;       // wave's output row (0/1)

    for (int i = tid; i < 4 * LCOLS * LSTRIDE; i += 256) xs[i] = 0;

    f32x4 acc[4][4];
#pragma unroll
    for (int mi = 0; mi < 4; ++mi)
#pragma unroll
        for (int ni = 0; ni < 4; ++ni) acc[mi][ni] = (f32x4){0.f, 0.f, 0.f, 0.f};

    const int y0 = yb * 2;
    // staging assignment: thread -> (input row r, col xcol)
    const int r = tid >> 6;
    const int xcol = tid & 63;
    const int yin = y0 - 1 + r;
    const bool valid = (yin >= 0) && (yin < HH);
    const int yc = valid ? yin : 0;
    const unsigned short* src = xt + (((size_t)(b * HH + yc) * WW + xcol) << 9);
    unsigned short* dstp = xs + (r * LCOLS + xcol + 1) * LSTRIDE;

    const unsigned short* wbase = wp + ((size_t)(b * 9) * COUT << 9);

#pragma unroll 1
    for (int ic = 0; ic < 8; ++ic) {
        __syncthreads();
        if (valid) {
            const short8* s8 = (const short8*)(src + ic * 64);
            short8* d8 = (short8*)dstp;
#pragma unroll
            for (int j = 0; j < 8; ++j) d8[j] = s8[j];
        }
        __syncthreads();
#pragma unroll
        for (int tap = 0; tap < 9; ++tap) {
            const int ky = tap / 3, kx = tap % 3;
            const unsigned short* wt = wbase + ((size_t)(tap * COUT) << 9);
#pragma unroll
            for (int ks = 0; ks < 2; ++ks) {
                const int kofs = ic * 64 + ks * 32 + l4 * 8;
                short8 af[4];
#pragma unroll
                for (int mi = 0; mi < 4; ++mi) {
                    int o = ob * 128 + o0w + mi * 16 + l15;
                    af[mi] = *(const short8*)(wt + ((size_t)o << 9) + kofs);
                }
                short8 bfr[4];
                const unsigned int cb = (unsigned)((row_w + ky) * LCOLS + kx + l15);
                const unsigned int kk = ks * 32 + l4 * 8;
#pragma unroll
                for (int ni = 0; ni < 4; ++ni) {
                    bfr[ni] = *(const short8*)(xs + (cb + ni * 16) * LSTRIDE + kk);
                }
#pragma unroll
                for (int mi = 0; mi < 4; ++mi)
#pragma unroll
                    for (int ni = 0; ni < 4; ++ni)
                        acc[mi][ni] = __builtin_amdgcn_mfma_f32_16x16x32_bf16(
                            af[mi], bfr[ni], acc[mi][ni], 0, 0, 0);
            }
        }
    }

    const int yout = y0 + row_w;
#pragma unroll
    for (int mi = 0; mi < 4; ++mi) {
        const int obase = ob * 128 + o0w + mi * 16 + l4 * 4;
#pragma unroll
        for (int rr = 0; rr < 4; ++rr) {
            const int o = obase + rr;
            const float bv = bias[o];
            float* orow = out + (((size_t)(b * COUT + o) * HH + yout) << 6);
#pragma unroll
            for (int ni = 0; ni < 4; ++ni) {
                orow[ni * 16 + l15] = acc[mi][ni][rr] + bv;
            }
        }
    }
}

extern "C" void kernel_launch(void* const* d_in, const int* in_sizes, int n_in,
                              void* d_out, int out_size, void* d_ws, size_t ws_size,
                              hipStream_t stream) {
    const float* x      = (const float*)d_in[0];
    const float* style  = (const float*)d_in[1];
    const float* weight = (const float*)d_in[2];
    const float* bias   = (const float*)d_in[3];
    float* out = (float*)d_out;

    unsigned short* wp = (unsigned short*)d_ws;                       // 8*9*512*512 bf16 = 37.75 MB
    unsigned short* xtg = wp + (size_t)BB * 9 * COUT * CIN;           // 8*64*64*512 bf16 = 33.55 MB

    xpose_kernel<<<dim3(16, HH, BB), 256, 0, stream>>>(x, xtg);
    modw_kernel<<<dim3(COUT, BB), 256, 0, stream>>>(weight, style, wp);
    conv_kernel<<<dim3(HH / 2, COUT / 128, BB), 256, 0, stream>>>(wp, xtg, bias, out);
}